// Round 3
// baseline (15472.792 us; speedup 1.0000x reference)
//
#include <hip/hip_runtime.h>

#define FPS_N 32768
#define FPS_M 2048
#define FPS_B 16
#define FPS_T 1024
#define NPAIR (FPS_N / 2)      // 16384 float2 pairs
#define KPT (NPAIR / FPS_T)    // 16 pairs per thread
#define NWAVE (FPS_T / 64)     // 16 waves

typedef float vf2 __attribute__((ext_vector_type(2)));

// One block per batch (sequential algorithm -> 16 CUs active by construction).
// amdgpu_waves_per_eu(4,4): pins BOTH min and max occupancy at 4 waves/EU so
// the allocator may use 128 VGPRs and the scheduler stops chasing 8 waves/EU.
// Round 1/2 lesson: launch_bounds(1024,4) alone still produced VGPR=64 and the
// compiler sank the 96-VGPR coord arrays into per-step L2 reloads (-> 9-17ms).
// Coords: 96 VGPRs register-resident. Running dist: 128 KiB LDS as pairs,
// ds_read_b64 + CONDITIONAL ds_write_b64 (updates total ~N ln m ~ 0.4% of
// evaluations -> most wave-pairs skip the write via s_cbranch_execz).
// Distance math on ext_vector_type(2) floats -> v_pk_{add,mul}_f32, bit-exact
// IEEE with numpy op order (dx*dx + dy*dy) + dz*dz, contract off, strict-> /
// lowest-index argmax ties (np.argmax first-occurrence).
__global__ __launch_bounds__(FPS_T)
__attribute__((amdgpu_waves_per_eu(4, 4)))
void fps_kernel(const float* __restrict__ pts, float* __restrict__ out) {
#pragma clang fp contract(off)
    __shared__ vf2 sdist[NPAIR];           // 128 KiB
    __shared__ float red_d[2][NWAVE];
    __shared__ int   red_i[2][NWAVE];

    const int b = blockIdx.x;
    const int tid = threadIdx.x;
    const float* __restrict__ X = pts + (size_t)b * 3 * FPS_N;
    const float* __restrict__ Y = X + FPS_N;
    const float* __restrict__ Z = Y + FPS_N;
    const vf2* __restrict__ X2 = (const vf2*)X;
    const vf2* __restrict__ Y2 = (const vf2*)Y;
    const vf2* __restrict__ Z2 = (const vf2*)Z;
    float* __restrict__ outb = out + (size_t)b * 3 * FPS_M;

    vf2 x[KPT], y[KPT], z[KPT];
#pragma unroll
    for (int k = 0; k < KPT; ++k) {
        const int q = k * FPS_T + tid;     // coalesced 8B loads, conflict-free LDS
        x[k] = X2[q];
        y[k] = Y2[q];
        z[k] = Z2[q];
        sdist[q] = (vf2){1e10f, 1e10f};
    }
    // first selected index is 0 (CUDA FPS convention)
    float lx = X[0], ly = Y[0], lz = Z[0];
    __syncthreads();

    for (int s = 0; s < FPS_M; ++s) {
        // emit current selection's coords (== gather by selected index)
        if (tid == 0) {
            outb[s] = lx;
            outb[FPS_M + s] = ly;
            outb[2 * FPS_M + s] = lz;
        }

        const vf2 lx2 = {lx, lx}, ly2 = {ly, ly}, lz2 = {lz, lz};
        float bd = -1.0f;
        int bi = 0;
#pragma unroll
        for (int k = 0; k < KPT; ++k) {
            const int q = k * FPS_T + tid;
            vf2 dx = x[k] - lx2;                       // v_pk_add_f32 (neg)
            vf2 dy = y[k] - ly2;
            vf2 dz = z[k] - lz2;
            vf2 d = (dx * dx + dy * dy) + dz * dz;     // v_pk_mul/add, numpy order
            vf2 dv = sdist[q];                         // ds_read_b64
            const bool w0 = d.x < dv.x;
            const bool w1 = d.y < dv.y;
            vf2 nd;
            nd.x = w0 ? d.x : dv.x;                    // min(dist, d)
            nd.y = w1 ? d.y : dv.y;
            if (w0 || w1) sdist[q] = nd;               // sparse: usually execz-skipped
            if (nd.x > bd) { bd = nd.x; bi = 2 * q; }  // strict >: lowest index wins
            if (nd.y > bd) { bd = nd.y; bi = 2 * q + 1; }
        }

        // 64-lane wave reduce: max dist, ties -> lowest index
#pragma unroll
        for (int off = 32; off > 0; off >>= 1) {
            float od = __shfl_down(bd, off);
            int   oi = __shfl_down(bi, off);
            if (od > bd || (od == bd && oi < bi)) { bd = od; bi = oi; }
        }
        const int wave = tid >> 6;
        const int par = s & 1;
        if ((tid & 63) == 0) { red_d[par][wave] = bd; red_i[par][wave] = bi; }
        __syncthreads();

        // all threads reduce the 16 wave partials (LDS broadcast reads);
        // parity double-buffer -> no second barrier.
        float wbd = red_d[par][0];
        int   wbi = red_i[par][0];
#pragma unroll
        for (int w = 1; w < NWAVE; ++w) {
            float od = red_d[par][w];
            int   oi = red_i[par][w];
            if (od > wbd || (od == wbd && oi < wbi)) { wbd = od; wbi = oi; }
        }

        // winner coords: wave-uniform address -> one L2 request per wave,
        // 3 independent loads (parallel latency)
        lx = X[wbi];
        ly = Y[wbi];
        lz = Z[wbi];
    }
}

extern "C" void kernel_launch(void* const* d_in, const int* in_sizes, int n_in,
                              void* d_out, int out_size, void* d_ws, size_t ws_size,
                              hipStream_t stream) {
    const float* pts = (const float*)d_in[0];   // [16, 3, 32768] fp32
    float* out = (float*)d_out;                 // [16, 3, 2048] fp32
    hipLaunchKernelGGL(fps_kernel, dim3(FPS_B), dim3(FPS_T), 0, stream, pts, out);
}

// Round 4
// 12615.334 us; speedup vs baseline: 1.2265x; 1.2265x over previous
//
#include <hip/hip_runtime.h>

#define FPS_N 32768
#define FPS_M 2048
#define FPS_B 16
#define FPS_T 512
#define NPAIR (FPS_N / 2)      // 16384 float2 pairs
#define KPT (NPAIR / FPS_T)    // 32 pairs per thread (64 points)
#define NWAVE (FPS_T / 64)     // 8 waves

typedef float vf2 __attribute__((ext_vector_type(2)));

// One block per batch (algorithm is sequential in m -> 16 CUs active).
// SHAPE CHANGE vs rounds 1-3: 512 threads (8 waves = exactly 2 waves/EU,
// pinned by amdgpu_waves_per_eu(2,2) -> 256-VGPR cap). Coords = 192 VGPRs
// with ~35 regs of slack, so RA can keep them resident. Rounds 1-3 ran 1024
// threads: demand ~125 vs cap 128 -> RA spilled everything (VGPR_Count=64,
// FETCH_SIZE ~16 GB of reload traffic, 9-17 ms).
// Running dist: 128 KiB LDS (float2, ds_read_b64; conditional write -> after
// warmup most wave-pairs skip it via s_cbranch_execz).
// Argmax: 4 independent accumulator chains (breaks the ~128-op cndmask
// dependency chain that 2 waves/SIMD can't hide), merged with explicit
// index tie-break. Semantics = np.argmax first occurrence: strict >,
// lowest global index on ties.
// Numerics bit-exact vs numpy: contract off, pk-f32 IEEE ops, sum order
// (dx*dx + dy*dy) + dz*dz.
__global__ __attribute__((amdgpu_flat_work_group_size(FPS_T, FPS_T)))
__attribute__((amdgpu_waves_per_eu(2, 2)))
void fps_kernel(const float* __restrict__ pts, float* __restrict__ out) {
#pragma clang fp contract(off)
    __shared__ vf2 sdist[NPAIR];           // 128 KiB
    __shared__ float red_d[2][NWAVE];
    __shared__ int   red_i[2][NWAVE];

    const int b = blockIdx.x;
    const int tid = threadIdx.x;
    const float* __restrict__ X = pts + (size_t)b * 3 * FPS_N;
    const float* __restrict__ Y = X + FPS_N;
    const float* __restrict__ Z = Y + FPS_N;
    const vf2* __restrict__ X2 = (const vf2*)X;
    const vf2* __restrict__ Y2 = (const vf2*)Y;
    const vf2* __restrict__ Z2 = (const vf2*)Z;
    float* __restrict__ outb = out + (size_t)b * 3 * FPS_M;

    vf2 x[KPT], y[KPT], z[KPT];            // 192 VGPRs, must stay resident
#pragma unroll
    for (int k = 0; k < KPT; ++k) {
        const int q = k * FPS_T + tid;     // coalesced 8B loads; b64 LDS conflict-free
        x[k] = X2[q];
        y[k] = Y2[q];
        z[k] = Z2[q];
        sdist[q] = (vf2){1e10f, 1e10f};
    }
    // first selected index is 0 (CUDA FPS convention)
    float lx = X[0], ly = Y[0], lz = Z[0];
    __syncthreads();

    for (int s = 0; s < FPS_M; ++s) {
        if (tid == 0) {                    // emit selection (gather by index)
            outb[s] = lx;
            outb[FPS_M + s] = ly;
            outb[2 * FPS_M + s] = lz;
        }

        const vf2 lx2 = {lx, lx}, ly2 = {ly, ly}, lz2 = {lz, lz};
        float bd[4] = {-1.0f, -1.0f, -1.0f, -1.0f};
        int   bi[4] = {0, 0, 0, 0};
#pragma unroll
        for (int k = 0; k < KPT; ++k) {
            const int q = k * FPS_T + tid;
            vf2 dx = x[k] - lx2;                       // v_pk_add_f32
            vf2 dy = y[k] - ly2;
            vf2 dz = z[k] - lz2;
            vf2 d = (dx * dx + dy * dy) + dz * dz;     // numpy op order, no fma
            vf2 dv = sdist[q];                         // ds_read_b64
            const bool w0 = d.x < dv.x;
            const bool w1 = d.y < dv.y;
            vf2 nd;
            nd.x = w0 ? d.x : dv.x;                    // min(dist, d)
            nd.y = w1 ? d.y : dv.y;
            if (w0 | w1) sdist[q] = nd;                // sparse write, execz-skipped
            const int c = k & 3;                       // 4 chains: break dep chain
            if (nd.x > bd[c]) { bd[c] = nd.x; bi[c] = 2 * q; }
            if (nd.y > bd[c]) { bd[c] = nd.y; bi[c] = 2 * q + 1; }
        }
        // merge chains (indices across chains unordered -> explicit tie-break)
        float tbd = bd[0];
        int   tbi = bi[0];
#pragma unroll
        for (int c = 1; c < 4; ++c)
            if (bd[c] > tbd || (bd[c] == tbd && bi[c] < tbi)) { tbd = bd[c]; tbi = bi[c]; }

        // 64-lane wave reduce: max dist, ties -> lowest global index
#pragma unroll
        for (int off = 32; off > 0; off >>= 1) {
            float od = __shfl_down(tbd, off);
            int   oi = __shfl_down(tbi, off);
            if (od > tbd || (od == tbd && oi < tbi)) { tbd = od; tbi = oi; }
        }
        const int wave = tid >> 6;
        const int par = s & 1;
        if ((tid & 63) == 0) { red_d[par][wave] = tbd; red_i[par][wave] = tbi; }
        __syncthreads();

        // every thread reduces the 8 wave partials (LDS broadcast reads);
        // parity double-buffer -> no second barrier.
        float wbd = red_d[par][0];
        int   wbi = red_i[par][0];
#pragma unroll
        for (int w = 1; w < NWAVE; ++w) {
            float od = red_d[par][w];
            int   oi = red_i[par][w];
            if (od > wbd || (od == wbd && oi < wbi)) { wbd = od; wbi = oi; }
        }

        // winner coords: wave-uniform address -> scalarized L2 load per wave
        lx = X[wbi];
        ly = Y[wbi];
        lz = Z[wbi];
    }
}

extern "C" void kernel_launch(void* const* d_in, const int* in_sizes, int n_in,
                              void* d_out, int out_size, void* d_ws, size_t ws_size,
                              hipStream_t stream) {
    const float* pts = (const float*)d_in[0];   // [16, 3, 32768] fp32
    float* out = (float*)d_out;                 // [16, 3, 2048] fp32
    hipLaunchKernelGGL(fps_kernel, dim3(FPS_B), dim3(FPS_T), 0, stream, pts, out);
}